// Round 9
// baseline (42.782 us; speedup 1.0000x reference)
//
#include <hip/hip_runtime.h>

#define N_DIM 2048
#define F_DIM 64

typedef __attribute__((ext_vector_type(4))) float  f32x4;
typedef __attribute__((ext_vector_type(8))) short  s16x8;
typedef __attribute__((ext_vector_type(8))) __bf16 bf16x8;

static __device__ __forceinline__ unsigned short f2bf(float f) {
  unsigned int u = __builtin_bit_cast(unsigned int, f);
  u += 0x7fffu + ((u >> 16) & 1u);      // RNE to bf16
  return (unsigned short)(u >> 16);
}

static __device__ __forceinline__ f32x4 ntload(const float* p) {
  return __builtin_nontemporal_load((const f32x4*)p);
}

// Prep (grid 72):
//  blocks 0..63  — MFMA B-fragments of bf16(v): lane l holds
//    B[k = 8*(l/16)+j][col = l%16], stored [kt(64)][tile(4)][lane(64)][j(8)]
//  blocks 64..71 — s_half[k] = 0.5 * sum_f v[k][f]^2
__global__ __launch_bounds__(256) void fm_prep(const float* __restrict__ v,
                                               unsigned short* __restrict__ vb,
                                               float* __restrict__ sh) {
  const int blk = blockIdx.x;
  const int tid = threadIdx.x;
  if (blk < 64) {
    const int g  = blk * 256 + tid;
    const int fl = g & 63;
    const int t  = (g >> 6) & 3;
    const int kt = g >> 8;
    const int kbase = kt * 32 + ((fl >> 4) << 3);
    const int f = t * 16 + (fl & 15);
    s16x8 a;
#pragma unroll
    for (int j = 0; j < 8; ++j)
      a[j] = (short)f2bf(v[(size_t)(kbase + j) * F_DIM + f]);
    *(s16x8*)(vb + (size_t)g * 8) = a;
  } else {
    const int k = (blk - 64) * 256 + tid;
    const f32x4* row = (const f32x4*)(v + (size_t)k * F_DIM);
    float s = 0.0f;
#pragma unroll
    for (int i = 0; i < 16; ++i) {
      f32x4 q = row[i];
      s += q[0]*q[0] + q[1]*q[1] + q[2]*q[2] + q[3]*q[3];
    }
    sh[k] = 0.5f * s;
  }
}

// Main: 512 blocks x 256 threads (4 waves). Block owns 32 rows of x.
// Wave w owns K-quarter [w*512, w*512+512), 16 iters of 32-k, computes
// BOTH 16-row tiles for all 4 F-tiles from the SAME 4 B-fragments.
// Pipeline (FIFO-separated): vb depth 1 issued FIRST, x depth 2 second.
// x loads NON-TEMPORAL: x is read exactly once — keep it out of L2/L3 so
// vb's 256 KiB working set stays L2-resident per XCD (contention theory).
// lin = x.w1 - 0.5*x^2.s fused in fp32 (w1/sh from LDS).
__global__ __launch_bounds__(256, 2) void fm_main(const float* __restrict__ x,
                                                  const float* __restrict__ w0,
                                                  const float* __restrict__ w1,
                                                  const unsigned short* __restrict__ vb,
                                                  const float* __restrict__ sh,
                                                  float* __restrict__ out) {
  const int tid  = threadIdx.x;
  const int lane = tid & 63;
  const int w    = tid >> 6;            // 0..3
  const int rowbase = blockIdx.x * 32;
  const int g8   = ((lane >> 4) << 3);  // k-subchunk offset within 32: 0,8,16,24

  __shared__ __align__(16) float w1L[N_DIM];     // 8 KiB
  __shared__ __align__(16) float shL[N_DIM];     // 8 KiB
  __shared__ __align__(16) f32x4 accW[3][8][64]; // 24 KiB (epilogue)
  __shared__ float linL[4][2][16];               // 512 B

  const int kw = w * 512;               // this wave's K range (16 iters of 32)
  const float* xA = x + (size_t)(rowbase + (lane & 15)) * N_DIM + kw + g8;
  const float* xB = xA + 16 * N_DIM;
  const unsigned short* vbase = vb + ((size_t)w * 4096 + lane) * 8;

  // ---- prologue: vb slot 0; x slots 0,1 ----
  s16x8 pb[2][4];
  f32x4 pxa[3], pxb[3], pxc[3], pxd[3];
#pragma unroll
  for (int t = 0; t < 4; ++t)
    pb[0][t] = *(const s16x8*)(vbase + t * 512);
#pragma unroll
  for (int s = 0; s < 2; ++s) {
    const int kc = s * 32;
    pxa[s] = ntload(xA + kc);
    pxb[s] = ntload(xA + kc + 4);
    pxc[s] = ntload(xB + kc);
    pxd[s] = ntload(xB + kc + 4);
  }

  // ---- stage w1/sh into LDS (256 thr x 8 floats each) ----
  {
    const int t8 = tid << 3;
    *(f32x4*)&w1L[t8]     = *(const f32x4*)(w1 + t8);
    *(f32x4*)&w1L[t8 + 4] = *(const f32x4*)(w1 + t8 + 4);
    *(f32x4*)&shL[t8]     = *(const f32x4*)(sh + t8);
    *(f32x4*)&shL[t8 + 4] = *(const f32x4*)(sh + t8 + 4);
  }
  __syncthreads();

  f32x4 acc[2][4] = {};
  float linA = 0.0f, linB = 0.0f;

#pragma unroll
  for (int s = 0; s < 16; ++s) {
    // vb prefetch FIRST (depth 1, L2-resident)
    if (s < 15) {
      const unsigned short* vbp = vbase + (size_t)(s + 1) * 2048;
#pragma unroll
      for (int t = 0; t < 4; ++t)
        pb[(s + 1) & 1][t] = *(const s16x8*)(vbp + t * 512);
    }
    // x prefetch SECOND (depth 2, HBM, non-temporal)
    if (s < 14) {
      const int kc = (s + 2) * 32;
      const int sl = (s + 2) % 3;
      pxa[sl] = ntload(xA + kc);
      pxb[sl] = ntload(xA + kc + 4);
      pxc[sl] = ntload(xB + kc);
      pxd[sl] = ntload(xB + kc + 4);
    }
    const int xs = s % 3;
    const int ki = kw + s * 32 + g8;
    f32x4 xa = pxa[xs], xb = pxb[xs], xc = pxc[xs], xd = pxd[xs];
    {
      f32x4 wa  = *(const f32x4*)(&w1L[ki]);
      f32x4 wb2 = *(const f32x4*)(&w1L[ki + 4]);
      f32x4 sa  = *(const f32x4*)(&shL[ki]);
      f32x4 sb2 = *(const f32x4*)(&shL[ki + 4]);
#pragma unroll
      for (int i = 0; i < 4; ++i) {
        linA = fmaf(xa[i], wa[i]  - xa[i] * sa[i],  linA);
        linA = fmaf(xb[i], wb2[i] - xb[i] * sb2[i], linA);
        linB = fmaf(xc[i], wa[i]  - xc[i] * sa[i],  linB);
        linB = fmaf(xd[i], wb2[i] - xd[i] * sb2[i], linB);
      }
    }
    bf16x8 Alo, Ahi;
#pragma unroll
    for (int i = 0; i < 4; ++i) {
      Alo[i]     = (__bf16)xa[i];
      Alo[4 + i] = (__bf16)xb[i];
      Ahi[i]     = (__bf16)xc[i];
      Ahi[4 + i] = (__bf16)xd[i];
    }
#pragma unroll
    for (int t = 0; t < 4; ++t) {
      bf16x8 Bv = __builtin_bit_cast(bf16x8, pb[s & 1][t]);
      acc[0][t] = __builtin_amdgcn_mfma_f32_16x16x32_bf16(Alo, Bv, acc[0][t], 0, 0, 0);
      acc[1][t] = __builtin_amdgcn_mfma_f32_16x16x32_bf16(Ahi, Bv, acc[1][t], 0, 0, 0);
    }
  }

  // ---- lin reduce: lanes {r,r+16,r+32,r+48} hold partials of row r ----
  linA += __shfl_xor(linA, 16);
  linA += __shfl_xor(linA, 32);
  linB += __shfl_xor(linB, 16);
  linB += __shfl_xor(linB, 32);
  if (lane < 16) {
    linL[w][0][lane] = linA;
    linL[w][1][lane] = linB;
  }

  // ---- cross-wave K-sum: waves 1..3 dump, wave 0 reduces ----
  if (w > 0) {
#pragma unroll
    for (int h = 0; h < 2; ++h)
#pragma unroll
      for (int t = 0; t < 4; ++t)
        accW[w - 1][h * 4 + t][lane] = acc[h][t];
  }
  __syncthreads();

  if (w == 0) {
#pragma unroll
    for (int ww = 0; ww < 3; ++ww)
#pragma unroll
      for (int h = 0; h < 2; ++h)
#pragma unroll
        for (int t = 0; t < 4; ++t)
          acc[h][t] += accW[ww][h * 4 + t][lane];

    // C layout: col = lane&15 (within F-tile t), row = 4*(lane>>4) + r
    float p[2][4];
#pragma unroll
    for (int h = 0; h < 2; ++h)
#pragma unroll
      for (int r = 0; r < 4; ++r) {
        float q = 0.0f;
#pragma unroll
        for (int t = 0; t < 4; ++t)
          q += acc[h][t][r] * acc[h][t][r];
        q += __shfl_xor(q, 1);
        q += __shfl_xor(q, 2);
        q += __shfl_xor(q, 4);
        q += __shfl_xor(q, 8);
        p[h][r] = q;
      }
    if ((lane & 15) == 0) {
      const int g = lane >> 4;
      const float w0v = w0[0];
#pragma unroll
      for (int h = 0; h < 2; ++h)
#pragma unroll
        for (int r = 0; r < 4; ++r) {
          const int row = g * 4 + r;
          float lt = linL[0][h][row] + linL[1][h][row]
                   + linL[2][h][row] + linL[3][h][row];
          __builtin_nontemporal_store(w0v + lt + 0.5f * p[h][r],
                                      &out[rowbase + h * 16 + row]);
        }
    }
  }
}

extern "C" void kernel_launch(void* const* d_in, const int* in_sizes, int n_in,
                              void* d_out, int out_size, void* d_ws, size_t ws_size,
                              hipStream_t stream) {
  const float* x  = (const float*)d_in[0];
  const float* w0 = (const float*)d_in[1];
  const float* w1 = (const float*)d_in[2];
  const float* v  = (const float*)d_in[3];
  float* out = (float*)d_out;

  unsigned short* vb = (unsigned short*)d_ws;           // 256 KiB
  float* sh = (float*)(vb + 131072);                    // 8 KiB

  fm_prep<<<72, 256, 0, stream>>>(v, vb, sh);
  fm_main<<<512, 256, 0, stream>>>(x, w0, w1, vb, sh, out);
}

// Round 10
// 37.829 us; speedup vs baseline: 1.1309x; 1.1309x over previous
//
#include <hip/hip_runtime.h>

#define N_DIM 2048
#define F_DIM 64

typedef __attribute__((ext_vector_type(4))) float  f32x4;
typedef __attribute__((ext_vector_type(8))) short  s16x8;
typedef __attribute__((ext_vector_type(8))) __bf16 bf16x8;

static __device__ __forceinline__ unsigned short f2bf(float f) {
  unsigned int u = __builtin_bit_cast(unsigned int, f);
  u += 0x7fffu + ((u >> 16) & 1u);      // RNE to bf16
  return (unsigned short)(u >> 16);
}

// Prep (grid 72):
//  blocks 0..63  — MFMA B-fragments of bf16(v): lane l holds
//    B[k = 8*(l/16)+j][col = l%16], stored [kt(64)][tile(4)][lane(64)][j(8)]
//  blocks 64..71 — s_half[k] = 0.5 * sum_f v[k][f]^2
__global__ __launch_bounds__(256) void fm_prep(const float* __restrict__ v,
                                               unsigned short* __restrict__ vb,
                                               float* __restrict__ sh) {
  const int blk = blockIdx.x;
  const int tid = threadIdx.x;
  if (blk < 64) {
    const int g  = blk * 256 + tid;
    const int fl = g & 63;
    const int t  = (g >> 6) & 3;
    const int kt = g >> 8;
    const int kbase = kt * 32 + ((fl >> 4) << 3);
    const int f = t * 16 + (fl & 15);
    s16x8 a;
#pragma unroll
    for (int j = 0; j < 8; ++j)
      a[j] = (short)f2bf(v[(size_t)(kbase + j) * F_DIM + f]);
    *(s16x8*)(vb + (size_t)g * 8) = a;
  } else {
    const int k = (blk - 64) * 256 + tid;
    const f32x4* row = (const f32x4*)(v + (size_t)k * F_DIM);
    float s = 0.0f;
#pragma unroll
    for (int i = 0; i < 16; ++i) {
      f32x4 q = row[i];
      s += q[0]*q[0] + q[1]*q[1] + q[2]*q[2] + q[3]*q[3];
    }
    sh[k] = 0.5f * s;
  }
}

// Main: 256 blocks x 512 threads (8 waves, 1 block/CU). Block owns 64 rows.
// Wave w owns K-eighth [w*256, w*256+256), 8 iters of 32-k, and computes
// FOUR 16-row tiles for all 4 F-tiles from the SAME 4 B-fragments
// (vb amortized 4x -> vb traffic 64 MiB total; 16 MFMA per 12 loads).
// Pipeline (FIFO-separated): vb depth 1 issued FIRST, x depth 2 second.
// lin = x.w1 - 0.5*x^2.s fused in fp32 (w1/sh from LDS).
__global__ __launch_bounds__(512, 2) void fm_main(const float* __restrict__ x,
                                                  const float* __restrict__ w0,
                                                  const float* __restrict__ w1,
                                                  const unsigned short* __restrict__ vb,
                                                  const float* __restrict__ sh,
                                                  float* __restrict__ out) {
  const int tid  = threadIdx.x;
  const int lane = tid & 63;
  const int w    = tid >> 6;            // 0..7
  const int rowbase = blockIdx.x * 64;
  const int g8   = ((lane >> 4) << 3);  // k-subchunk offset within 32: 0,8,16,24

  __shared__ __align__(16) float w1L[N_DIM];      // 8 KiB
  __shared__ __align__(16) float shL[N_DIM];      // 8 KiB
  __shared__ __align__(16) f32x4 accW[4][16][64]; // 64 KiB (epilogue)
  __shared__ float linL[8][4][16];                // 2 KiB

  const int kw = w * 256;               // this wave's K range (8 iters of 32)
  const float* xT0 = x + (size_t)(rowbase + (lane & 15)) * N_DIM + kw + g8;
  const float* xT1 = xT0 + 16 * N_DIM;
  const float* xT2 = xT0 + 32 * N_DIM;
  const float* xT3 = xT0 + 48 * N_DIM;
  // wave's vb range: kt = w*8 + s  ->  frag base (kt*4 + t)*64*8
  const unsigned short* vbase = vb + ((size_t)(w * 32) * 64 + lane) * 8;

  // ---- prologue: vb slot 0; x slots 0,1 ----
  s16x8 pb[2][4];
  f32x4 pxa[3][4], pxb[3][4];
#pragma unroll
  for (int t = 0; t < 4; ++t)
    pb[0][t] = *(const s16x8*)(vbase + t * 512);
#pragma unroll
  for (int s = 0; s < 2; ++s) {
    const int kc = s * 32;
    pxa[s][0] = *(const f32x4*)(xT0 + kc);  pxb[s][0] = *(const f32x4*)(xT0 + kc + 4);
    pxa[s][1] = *(const f32x4*)(xT1 + kc);  pxb[s][1] = *(const f32x4*)(xT1 + kc + 4);
    pxa[s][2] = *(const f32x4*)(xT2 + kc);  pxb[s][2] = *(const f32x4*)(xT2 + kc + 4);
    pxa[s][3] = *(const f32x4*)(xT3 + kc);  pxb[s][3] = *(const f32x4*)(xT3 + kc + 4);
  }

  // ---- stage w1/sh into LDS (512 thr x 4 floats each) ----
  {
    const int t4 = tid << 2;
    *(f32x4*)&w1L[t4] = *(const f32x4*)(w1 + t4);
    *(f32x4*)&shL[t4] = *(const f32x4*)(sh + t4);
  }
  __syncthreads();

  f32x4 acc[4][4] = {};
  float lin[4] = {0.f, 0.f, 0.f, 0.f};

#pragma unroll
  for (int s = 0; s < 8; ++s) {
    // vb prefetch FIRST (depth 1)
    if (s < 7) {
      const unsigned short* vbp = vbase + (size_t)(s + 1) * 2048;
#pragma unroll
      for (int t = 0; t < 4; ++t)
        pb[(s + 1) & 1][t] = *(const s16x8*)(vbp + t * 512);
    }
    // x prefetch SECOND (depth 2)
    if (s < 6) {
      const int kc = (s + 2) * 32;
      const int sl = (s + 2) % 3;
      pxa[sl][0] = *(const f32x4*)(xT0 + kc);  pxb[sl][0] = *(const f32x4*)(xT0 + kc + 4);
      pxa[sl][1] = *(const f32x4*)(xT1 + kc);  pxb[sl][1] = *(const f32x4*)(xT1 + kc + 4);
      pxa[sl][2] = *(const f32x4*)(xT2 + kc);  pxb[sl][2] = *(const f32x4*)(xT2 + kc + 4);
      pxa[sl][3] = *(const f32x4*)(xT3 + kc);  pxb[sl][3] = *(const f32x4*)(xT3 + kc + 4);
    }
    const int xs = s % 3;
    const int ki = kw + s * 32 + g8;
    f32x4 wa  = *(const f32x4*)(&w1L[ki]);
    f32x4 wb2 = *(const f32x4*)(&w1L[ki + 4]);
    f32x4 sa  = *(const f32x4*)(&shL[ki]);
    f32x4 sb2 = *(const f32x4*)(&shL[ki + 4]);

    bf16x8 A[4];
#pragma unroll
    for (int rt = 0; rt < 4; ++rt) {
      f32x4 xa = pxa[xs][rt], xb = pxb[xs][rt];
#pragma unroll
      for (int i = 0; i < 4; ++i) {
        lin[rt] = fmaf(xa[i], wa[i]  - xa[i] * sa[i],  lin[rt]);
        lin[rt] = fmaf(xb[i], wb2[i] - xb[i] * sb2[i], lin[rt]);
        A[rt][i]     = (__bf16)xa[i];
        A[rt][4 + i] = (__bf16)xb[i];
      }
    }
#pragma unroll
    for (int t = 0; t < 4; ++t) {
      bf16x8 Bv = __builtin_bit_cast(bf16x8, pb[s & 1][t]);
#pragma unroll
      for (int rt = 0; rt < 4; ++rt)
        acc[rt][t] = __builtin_amdgcn_mfma_f32_16x16x32_bf16(A[rt], Bv, acc[rt][t], 0, 0, 0);
    }
  }

  // ---- lin reduce: lanes {r,r+16,r+32,r+48} hold partials of row r ----
#pragma unroll
  for (int rt = 0; rt < 4; ++rt) {
    lin[rt] += __shfl_xor(lin[rt], 16);
    lin[rt] += __shfl_xor(lin[rt], 32);
  }
  if (lane < 16) {
#pragma unroll
    for (int rt = 0; rt < 4; ++rt)
      linL[w][rt][lane] = lin[rt];
  }

  // ---- cross-wave K-sum: 8 -> 4 -> 1 via LDS ----
  if (w >= 4) {
#pragma unroll
    for (int rt = 0; rt < 4; ++rt)
#pragma unroll
      for (int t = 0; t < 4; ++t)
        accW[w - 4][rt * 4 + t][lane] = acc[rt][t];
  }
  __syncthreads();
  if (w < 4) {
#pragma unroll
    for (int rt = 0; rt < 4; ++rt)
#pragma unroll
      for (int t = 0; t < 4; ++t)
        acc[rt][t] += accW[w][rt * 4 + t][lane];
  }
  __syncthreads();
  if (w >= 1 && w < 4) {
#pragma unroll
    for (int rt = 0; rt < 4; ++rt)
#pragma unroll
      for (int t = 0; t < 4; ++t)
        accW[w - 1][rt * 4 + t][lane] = acc[rt][t];
  }
  __syncthreads();

  if (w == 0) {
#pragma unroll
    for (int ww = 0; ww < 3; ++ww)
#pragma unroll
      for (int rt = 0; rt < 4; ++rt)
#pragma unroll
        for (int t = 0; t < 4; ++t)
          acc[rt][t] += accW[ww][rt * 4 + t][lane];

    // C layout: col = lane&15 (within F-tile t), row-in-tile = 4*(lane>>4)+r
    float p[4][4];
#pragma unroll
    for (int rt = 0; rt < 4; ++rt)
#pragma unroll
      for (int r = 0; r < 4; ++r) {
        float q = 0.0f;
#pragma unroll
        for (int t = 0; t < 4; ++t)
          q += acc[rt][t][r] * acc[rt][t][r];
        q += __shfl_xor(q, 1);
        q += __shfl_xor(q, 2);
        q += __shfl_xor(q, 4);
        q += __shfl_xor(q, 8);
        p[rt][r] = q;
      }
    if ((lane & 15) == 0) {
      const int g = lane >> 4;
      const float w0v = w0[0];
#pragma unroll
      for (int rt = 0; rt < 4; ++rt)
#pragma unroll
        for (int r = 0; r < 4; ++r) {
          const int row = g * 4 + r;
          float lt = 0.0f;
#pragma unroll
          for (int ww = 0; ww < 8; ++ww)
            lt += linL[ww][rt][row];
          out[rowbase + rt * 16 + row] = w0v + lt + 0.5f * p[rt][r];
        }
    }
  }
}

extern "C" void kernel_launch(void* const* d_in, const int* in_sizes, int n_in,
                              void* d_out, int out_size, void* d_ws, size_t ws_size,
                              hipStream_t stream) {
  const float* x  = (const float*)d_in[0];
  const float* w0 = (const float*)d_in[1];
  const float* w1 = (const float*)d_in[2];
  const float* v  = (const float*)d_in[3];
  float* out = (float*)d_out;

  unsigned short* vb = (unsigned short*)d_ws;           // 256 KiB
  float* sh = (float*)(vb + 131072);                    // 8 KiB

  fm_prep<<<72, 256, 0, stream>>>(v, vb, sh);
  fm_main<<<256, 512, 0, stream>>>(x, w0, w1, vb, sh, out);
}

// Round 11
// 34.295 us; speedup vs baseline: 1.2475x; 1.1030x over previous
//
#include <hip/hip_runtime.h>

#define N_DIM 2048
#define F_DIM 64

typedef __attribute__((ext_vector_type(4))) float  f32x4;
typedef __attribute__((ext_vector_type(8))) short  s16x8;
typedef __attribute__((ext_vector_type(8))) __bf16 bf16x8;

static __device__ __forceinline__ unsigned short f2bf(float f) {
  unsigned int u = __builtin_bit_cast(unsigned int, f);
  u += 0x7fffu + ((u >> 16) & 1u);      // RNE to bf16
  return (unsigned short)(u >> 16);
}

static __device__ __forceinline__ f32x4 ntload(const float* p) {
  return __builtin_nontemporal_load((const f32x4*)p);
}

// Prep (grid 72):
//  blocks 0..63  — MFMA B-fragments of bf16(v): lane l holds
//    B[k = 8*(l/16)+j][col = l%16], stored [kt(64)][tile(4)][lane(64)][j(8)]
//  blocks 64..71 — s_half[k] = 0.5 * sum_f v[k][f]^2
__global__ __launch_bounds__(256) void fm_prep(const float* __restrict__ v,
                                               unsigned short* __restrict__ vb,
                                               float* __restrict__ sh) {
  const int blk = blockIdx.x;
  const int tid = threadIdx.x;
  if (blk < 64) {
    const int g  = blk * 256 + tid;
    const int fl = g & 63;
    const int t  = (g >> 6) & 3;
    const int kt = g >> 8;
    const int kbase = kt * 32 + ((fl >> 4) << 3);
    const int f = t * 16 + (fl & 15);
    s16x8 a;
#pragma unroll
    for (int j = 0; j < 8; ++j)
      a[j] = (short)f2bf(v[(size_t)(kbase + j) * F_DIM + f]);
    *(s16x8*)(vb + (size_t)g * 8) = a;
  } else {
    const int k = (blk - 64) * 256 + tid;
    const f32x4* row = (const f32x4*)(v + (size_t)k * F_DIM);
    float s = 0.0f;
#pragma unroll
    for (int i = 0; i < 16; ++i) {
      f32x4 q = row[i];
      s += q[0]*q[0] + q[1]*q[1] + q[2]*q[2] + q[3]*q[3];
    }
    sh[k] = 0.5f * s;
  }
}

// Main: 512 blocks x 256 threads (4 waves). Block owns 32 rows of x.
// Wave w owns K-quarter [w*512, w*512+512), 16 iters of 32-k, computes
// BOTH 16-row tiles for all 4 F-tiles from the SAME 4 B-fragments.
// x is NON-TEMPORAL loaded line-coalesced (each 128B line by exactly one
// instruction -> fetched once, L2 bypassed), staged through a wave-private
// XOR-swizzled LDS double buffer, and read back in MFMA A-fragment layout.
// vb stays cached (L2-hot). FIFO: vb issued before the x stream each iter.
// lin = x.w1 - 0.5*x^2.s fused in fp32 (w1/sh from LDS).
__global__ __launch_bounds__(256, 2) void fm_main(const float* __restrict__ x,
                                                  const float* __restrict__ w0,
                                                  const float* __restrict__ w1,
                                                  const unsigned short* __restrict__ vb,
                                                  const float* __restrict__ sh,
                                                  float* __restrict__ out) {
  const int tid  = threadIdx.x;
  const int lane = tid & 63;
  const int w    = tid >> 6;            // 0..3
  const int rowbase = blockIdx.x * 32;
  const int g8   = ((lane >> 4) << 3);  // fragment k-subchunk: 0,8,16,24

  __shared__ __align__(16) char  xS[4][2][4096]; // 32 KiB wave-private dbuf
  __shared__ __align__(16) float w1L[N_DIM];     // 8 KiB
  __shared__ __align__(16) float shL[N_DIM];     // 8 KiB
  __shared__ __align__(16) f32x4 accW[3][8][64]; // 24 KiB (epilogue)
  __shared__ float linL[4][2][16];               // 512 B

  const int kw = w * 512;               // this wave's K range (16 iters of 32)

  // ---- staging geometry: 4 nt instrs cover 32 rows x 128B, line-exact ----
  const int srow = lane >> 3;           // 0..7 within 8-row group
  const int sc   = lane & 7;            // 16B chunk within the row line
  const float* xg0 = x + (size_t)(rowbase + srow) * N_DIM + kw + sc * 4;
  // LDS dst (bytes, within wave slab): swizzle col ^= (row&7)<<4; row&7==srow
  int dst[4];
#pragma unroll
  for (int i = 0; i < 4; ++i)
    dst[i] = i * 1024 + srow * 128 + ((sc << 4) ^ (srow << 4));
  char* wb = &xS[w][0][0];

  // ---- fragment-read geometry ----
  const int frow = lane & 15;
  const int fo   = ((lane >> 4) << 5) ^ ((lane & 7) << 4); // swizzled in-row byte
  const int frA  = frow * 128 + fo;     // tile0 (rows 0-15)
  const int frB  = frA + 2048;          // tile1 (rows 16-31)

  const unsigned short* vbase = vb + ((size_t)w * 4096 + lane) * 8;

  // ---- prologue ----
  f32x4 xr[2][4];
  s16x8 pb[2][4];
#pragma unroll
  for (int i = 0; i < 4; ++i)           // x(0)
    xr[0][i] = ntload(xg0 + (size_t)i * 8 * N_DIM);
#pragma unroll
  for (int i = 0; i < 4; ++i)           // x(1)
    xr[1][i] = ntload(xg0 + (size_t)i * 8 * N_DIM + 32);
#pragma unroll
  for (int t = 0; t < 4; ++t)           // vb(0)
    pb[0][t] = *(const s16x8*)(vbase + t * 512);
  {
    const int t8 = tid << 3;            // stage w1/sh
    *(f32x4*)&w1L[t8]     = *(const f32x4*)(w1 + t8);
    *(f32x4*)&w1L[t8 + 4] = *(const f32x4*)(w1 + t8 + 4);
    *(f32x4*)&shL[t8]     = *(const f32x4*)(sh + t8);
    *(f32x4*)&shL[t8 + 4] = *(const f32x4*)(sh + t8 + 4);
  }
#pragma unroll
  for (int i = 0; i < 4; ++i)           // ds_write x(0) -> slot 0
    *(f32x4*)(wb + dst[i]) = xr[0][i];
  __syncthreads();

  f32x4 acc[2][4] = {};
  float linA = 0.0f, linB = 0.0f;

#pragma unroll
  for (int s = 0; s < 16; ++s) {
    const int slot = s & 1;
    const char* xq = wb + slot * 4096;
    // 1. fragment reads from slot (written last iter)
    f32x4 fa0 = *(const f32x4*)(xq + frA);
    f32x4 fa1 = *(const f32x4*)(xq + (frA ^ 16));
    f32x4 fb0 = *(const f32x4*)(xq + frB);
    f32x4 fb1 = *(const f32x4*)(xq + (frB ^ 16));
    const int ki = kw + s * 32 + g8;
    f32x4 wa  = *(const f32x4*)(&w1L[ki]);
    f32x4 wb2 = *(const f32x4*)(&w1L[ki + 4]);
    f32x4 sa  = *(const f32x4*)(&shL[ki]);
    f32x4 sb2 = *(const f32x4*)(&shL[ki + 4]);
    // 2. vb prefetch FIRST in vmem order (depth 1, cached)
    if (s < 15) {
      const unsigned short* vbp = vbase + (size_t)(s + 1) * 2048;
#pragma unroll
      for (int t = 0; t < 4; ++t)
        pb[(s + 1) & 1][t] = *(const s16x8*)(vbp + t * 512);
    }
    // 3. ds_write x(s+1) (arrived; waits only the x stream) -> other slot
    if (s < 15) {
      char* q2 = wb + (slot ^ 1) * 4096;
#pragma unroll
      for (int i = 0; i < 4; ++i)
        *(f32x4*)(q2 + dst[i]) = xr[(s + 1) & 1][i];
    }
    // 4. issue nt x(s+2)
    if (s < 14) {
#pragma unroll
      for (int i = 0; i < 4; ++i)
        xr[s & 1][i] = ntload(xg0 + (size_t)i * 8 * N_DIM + (s + 2) * 32);
    }
    // 5. compute
#pragma unroll
    for (int i = 0; i < 4; ++i) {
      linA = fmaf(fa0[i], wa[i]  - fa0[i] * sa[i],  linA);
      linA = fmaf(fa1[i], wb2[i] - fa1[i] * sb2[i], linA);
      linB = fmaf(fb0[i], wa[i]  - fb0[i] * sa[i],  linB);
      linB = fmaf(fb1[i], wb2[i] - fb1[i] * sb2[i], linB);
    }
    bf16x8 Alo, Ahi;
#pragma unroll
    for (int i = 0; i < 4; ++i) {
      Alo[i]     = (__bf16)fa0[i];
      Alo[4 + i] = (__bf16)fa1[i];
      Ahi[i]     = (__bf16)fb0[i];
      Ahi[4 + i] = (__bf16)fb1[i];
    }
#pragma unroll
    for (int t = 0; t < 4; ++t) {
      bf16x8 Bv = __builtin_bit_cast(bf16x8, pb[slot][t]);
      acc[0][t] = __builtin_amdgcn_mfma_f32_16x16x32_bf16(Alo, Bv, acc[0][t], 0, 0, 0);
      acc[1][t] = __builtin_amdgcn_mfma_f32_16x16x32_bf16(Ahi, Bv, acc[1][t], 0, 0, 0);
    }
  }

  // ---- lin reduce: lanes {r,r+16,r+32,r+48} hold partials of row r ----
  linA += __shfl_xor(linA, 16);
  linA += __shfl_xor(linA, 32);
  linB += __shfl_xor(linB, 16);
  linB += __shfl_xor(linB, 32);
  if (lane < 16) {
    linL[w][0][lane] = linA;
    linL[w][1][lane] = linB;
  }

  // ---- cross-wave K-sum: waves 1..3 dump, wave 0 reduces ----
  if (w > 0) {
#pragma unroll
    for (int h = 0; h < 2; ++h)
#pragma unroll
      for (int t = 0; t < 4; ++t)
        accW[w - 1][h * 4 + t][lane] = acc[h][t];
  }
  __syncthreads();

  if (w == 0) {
#pragma unroll
    for (int ww = 0; ww < 3; ++ww)
#pragma unroll
      for (int h = 0; h < 2; ++h)
#pragma unroll
        for (int t = 0; t < 4; ++t)
          acc[h][t] += accW[ww][h * 4 + t][lane];

    // C layout: col = lane&15 (within F-tile t), row = 4*(lane>>4) + r
    float p[2][4];
#pragma unroll
    for (int h = 0; h < 2; ++h)
#pragma unroll
      for (int r = 0; r < 4; ++r) {
        float q = 0.0f;
#pragma unroll
        for (int t = 0; t < 4; ++t)
          q += acc[h][t][r] * acc[h][t][r];
        q += __shfl_xor(q, 1);
        q += __shfl_xor(q, 2);
        q += __shfl_xor(q, 4);
        q += __shfl_xor(q, 8);
        p[h][r] = q;
      }
    if ((lane & 15) == 0) {
      const int g = lane >> 4;
      const float w0v = w0[0];
#pragma unroll
      for (int h = 0; h < 2; ++h)
#pragma unroll
        for (int r = 0; r < 4; ++r) {
          const int row = g * 4 + r;
          float lt = linL[0][h][row] + linL[1][h][row]
                   + linL[2][h][row] + linL[3][h][row];
          out[rowbase + h * 16 + row] = w0v + lt + 0.5f * p[h][r];
        }
    }
  }
}

extern "C" void kernel_launch(void* const* d_in, const int* in_sizes, int n_in,
                              void* d_out, int out_size, void* d_ws, size_t ws_size,
                              hipStream_t stream) {
  const float* x  = (const float*)d_in[0];
  const float* w0 = (const float*)d_in[1];
  const float* w1 = (const float*)d_in[2];
  const float* v  = (const float*)d_in[3];
  float* out = (float*)d_out;

  unsigned short* vb = (unsigned short*)d_ws;           // 256 KiB
  float* sh = (float*)(vb + 131072);                    // 8 KiB

  fm_prep<<<72, 256, 0, stream>>>(v, vb, sh);
  fm_main<<<512, 256, 0, stream>>>(x, w0, w1, vb, sh, out);
}

// Round 12
// 33.069 us; speedup vs baseline: 1.2937x; 1.0371x over previous
//
#include <hip/hip_runtime.h>

#define N_DIM 2048
#define F_DIM 64

typedef __attribute__((ext_vector_type(4))) float  f32x4;
typedef __attribute__((ext_vector_type(8))) short  s16x8;
typedef __attribute__((ext_vector_type(8))) __bf16 bf16x8;

static __device__ __forceinline__ unsigned short f2bf(float f) {
  unsigned int u = __builtin_bit_cast(unsigned int, f);
  u += 0x7fffu + ((u >> 16) & 1u);      // RNE to bf16
  return (unsigned short)(u >> 16);
}

// Prep (grid 72):
//  blocks 0..63  — MFMA B-fragments of bf16(v): lane l holds
//    B[k = 8*(l/16)+j][col = l%16], stored [kt(64)][tile(4)][lane(64)][j(8)]
//  blocks 64..71 — s_half[k] = 0.5 * sum_f v[k][f]^2
__global__ __launch_bounds__(256) void fm_prep(const float* __restrict__ v,
                                               unsigned short* __restrict__ vb,
                                               float* __restrict__ sh) {
  const int blk = blockIdx.x;
  const int tid = threadIdx.x;
  if (blk < 64) {
    const int g  = blk * 256 + tid;
    const int fl = g & 63;
    const int t  = (g >> 6) & 3;
    const int kt = g >> 8;
    const int kbase = kt * 32 + ((fl >> 4) << 3);
    const int f = t * 16 + (fl & 15);
    s16x8 a;
#pragma unroll
    for (int j = 0; j < 8; ++j)
      a[j] = (short)f2bf(v[(size_t)(kbase + j) * F_DIM + f]);
    *(s16x8*)(vb + (size_t)g * 8) = a;
  } else {
    const int k = (blk - 64) * 256 + tid;
    const f32x4* row = (const f32x4*)(v + (size_t)k * F_DIM);
    float s = 0.0f;
#pragma unroll
    for (int i = 0; i < 16; ++i) {
      f32x4 q = row[i];
      s += q[0]*q[0] + q[1]*q[1] + q[2]*q[2] + q[3]*q[3];
    }
    sh[k] = 0.5f * s;
  }
}

// Main: 512 blocks x 256 threads (4 waves) — R7 skeleton, K-STEP 64.
// Wave w owns K-quarter [w*512, w*512+512) in 8 iters of 64-k; computes
// BOTH 16-row tiles for all 4 F-tiles from the same B-fragments.
// Per iteration the 4 x-load instructions per row-set cover 256 B
// CONTIGUOUS per row, issued back-to-back -> one DRAM page activate
// serves 256 B (vs 128 B at k-step 32): halves activate rate.
// Pipeline: depth-1 double-buffer, vb issued FIRST (FIFO separation).
// lin = x.w1 - 0.5*x^2.s fused in fp32 (w1/sh from LDS).
__global__ __launch_bounds__(256, 2) void fm_main(const float* __restrict__ x,
                                                  const float* __restrict__ w0,
                                                  const float* __restrict__ w1,
                                                  const unsigned short* __restrict__ vb,
                                                  const float* __restrict__ sh,
                                                  float* __restrict__ out) {
  const int tid  = threadIdx.x;
  const int lane = tid & 63;
  const int w    = tid >> 6;            // 0..3
  const int rowbase = blockIdx.x * 32;
  const int g8   = ((lane >> 4) << 3);  // k-subchunk offset within 32: 0,8,16,24

  __shared__ __align__(16) float w1L[N_DIM];     // 8 KiB
  __shared__ __align__(16) float shL[N_DIM];     // 8 KiB
  __shared__ __align__(16) f32x4 accW[3][8][64]; // 24 KiB (epilogue)
  __shared__ float linL[4][2][16];               // 512 B

  const int kw = w * 512;               // this wave's K range (8 iters of 64)
  const float* xA = x + (size_t)(rowbase + (lane & 15)) * N_DIM + kw + g8;
  const float* xB = xA + 16 * N_DIM;
  const unsigned short* vbase = vb + ((size_t)w * 4096 + lane) * 8;

  // ---- prologue: vb(0) then x(0); each iter covers 2 k-chunks (q = c*4+t) ----
  s16x8 pb[2][8];
  f32x4 px[2][8];
#pragma unroll
  for (int q = 0; q < 8; ++q)
    pb[0][q] = *(const s16x8*)(vbase + (size_t)(q >> 2) * 2048 + (q & 3) * 512);
#pragma unroll
  for (int c = 0; c < 2; ++c) {
    px[0][c * 4 + 0] = *(const f32x4*)(xA + 32 * c);
    px[0][c * 4 + 1] = *(const f32x4*)(xA + 32 * c + 4);
    px[0][c * 4 + 2] = *(const f32x4*)(xB + 32 * c);
    px[0][c * 4 + 3] = *(const f32x4*)(xB + 32 * c + 4);
  }

  // ---- stage w1/sh into LDS (256 thr x 8 floats each) ----
  {
    const int t8 = tid << 3;
    *(f32x4*)&w1L[t8]     = *(const f32x4*)(w1 + t8);
    *(f32x4*)&w1L[t8 + 4] = *(const f32x4*)(w1 + t8 + 4);
    *(f32x4*)&shL[t8]     = *(const f32x4*)(sh + t8);
    *(f32x4*)&shL[t8 + 4] = *(const f32x4*)(sh + t8 + 4);
  }
  __syncthreads();

  f32x4 acc[2][4] = {};
  float linA = 0.0f, linB = 0.0f;

#pragma unroll
  for (int s = 0; s < 8; ++s) {
    const int cur = s & 1, nxt = cur ^ 1;
    if (s < 7) {
      // vb prefetch FIRST (depth 1, L2-resident)
      const unsigned short* vbp = vbase + (size_t)(2 * (s + 1)) * 2048;
#pragma unroll
      for (int q = 0; q < 8; ++q)
        pb[nxt][q] = *(const s16x8*)(vbp + (size_t)(q >> 2) * 2048 + (q & 3) * 512);
      // x prefetch SECOND (depth 1): next 64-k window, 256 B/row contiguous
      const int kc = (s + 1) * 64;
#pragma unroll
      for (int c = 0; c < 2; ++c) {
        px[nxt][c * 4 + 0] = *(const f32x4*)(xA + kc + 32 * c);
        px[nxt][c * 4 + 1] = *(const f32x4*)(xA + kc + 32 * c + 4);
        px[nxt][c * 4 + 2] = *(const f32x4*)(xB + kc + 32 * c);
        px[nxt][c * 4 + 3] = *(const f32x4*)(xB + kc + 32 * c + 4);
      }
    }
    // compute: two independent 32-k chunks (sequenced to cap reg pressure)
#pragma unroll
    for (int c = 0; c < 2; ++c) {
      const int ki = kw + s * 64 + c * 32 + g8;
      f32x4 wa  = *(const f32x4*)(&w1L[ki]);
      f32x4 wb2 = *(const f32x4*)(&w1L[ki + 4]);
      f32x4 sa  = *(const f32x4*)(&shL[ki]);
      f32x4 sb2 = *(const f32x4*)(&shL[ki + 4]);
      f32x4 xa = px[cur][c * 4 + 0], xb = px[cur][c * 4 + 1];
      f32x4 xc = px[cur][c * 4 + 2], xd = px[cur][c * 4 + 3];
#pragma unroll
      for (int i = 0; i < 4; ++i) {
        linA = fmaf(xa[i], wa[i]  - xa[i] * sa[i],  linA);
        linA = fmaf(xb[i], wb2[i] - xb[i] * sb2[i], linA);
        linB = fmaf(xc[i], wa[i]  - xc[i] * sa[i],  linB);
        linB = fmaf(xd[i], wb2[i] - xd[i] * sb2[i], linB);
      }
      bf16x8 Alo, Ahi;
#pragma unroll
      for (int i = 0; i < 4; ++i) {
        Alo[i]     = (__bf16)xa[i];
        Alo[4 + i] = (__bf16)xb[i];
        Ahi[i]     = (__bf16)xc[i];
        Ahi[4 + i] = (__bf16)xd[i];
      }
#pragma unroll
      for (int t = 0; t < 4; ++t) {
        bf16x8 Bv = __builtin_bit_cast(bf16x8, pb[cur][c * 4 + t]);
        acc[0][t] = __builtin_amdgcn_mfma_f32_16x16x32_bf16(Alo, Bv, acc[0][t], 0, 0, 0);
        acc[1][t] = __builtin_amdgcn_mfma_f32_16x16x32_bf16(Ahi, Bv, acc[1][t], 0, 0, 0);
      }
    }
  }

  // ---- lin reduce: lanes {r,r+16,r+32,r+48} hold partials of row r ----
  linA += __shfl_xor(linA, 16);
  linA += __shfl_xor(linA, 32);
  linB += __shfl_xor(linB, 16);
  linB += __shfl_xor(linB, 32);
  if (lane < 16) {
    linL[w][0][lane] = linA;
    linL[w][1][lane] = linB;
  }

  // ---- cross-wave K-sum: waves 1..3 dump, wave 0 reduces ----
  if (w > 0) {
#pragma unroll
    for (int h = 0; h < 2; ++h)
#pragma unroll
      for (int t = 0; t < 4; ++t)
        accW[w - 1][h * 4 + t][lane] = acc[h][t];
  }
  __syncthreads();

  if (w == 0) {
#pragma unroll
    for (int ww = 0; ww < 3; ++ww)
#pragma unroll
      for (int h = 0; h < 2; ++h)
#pragma unroll
        for (int t = 0; t < 4; ++t)
          acc[h][t] += accW[ww][h * 4 + t][lane];

    // C layout: col = lane&15 (within F-tile t), row = 4*(lane>>4) + r
    float p[2][4];
#pragma unroll
    for (int h = 0; h < 2; ++h)
#pragma unroll
      for (int r = 0; r < 4; ++r) {
        float q = 0.0f;
#pragma unroll
        for (int t = 0; t < 4; ++t)
          q += acc[h][t][r] * acc[h][t][r];
        q += __shfl_xor(q, 1);
        q += __shfl_xor(q, 2);
        q += __shfl_xor(q, 4);
        q += __shfl_xor(q, 8);
        p[h][r] = q;
      }
    if ((lane & 15) == 0) {
      const int g = lane >> 4;
      const float w0v = w0[0];
#pragma unroll
      for (int h = 0; h < 2; ++h)
#pragma unroll
        for (int r = 0; r < 4; ++r) {
          const int row = g * 4 + r;
          float lt = linL[0][h][row] + linL[1][h][row]
                   + linL[2][h][row] + linL[3][h][row];
          out[rowbase + h * 16 + row] = w0v + lt + 0.5f * p[h][r];
        }
    }
  }
}

extern "C" void kernel_launch(void* const* d_in, const int* in_sizes, int n_in,
                              void* d_out, int out_size, void* d_ws, size_t ws_size,
                              hipStream_t stream) {
  const float* x  = (const float*)d_in[0];
  const float* w0 = (const float*)d_in[1];
  const float* w1 = (const float*)d_in[2];
  const float* v  = (const float*)d_in[3];
  float* out = (float*)d_out;

  unsigned short* vb = (unsigned short*)d_ws;           // 256 KiB
  float* sh = (float*)(vb + 131072);                    // 8 KiB

  fm_prep<<<72, 256, 0, stream>>>(v, vb, sh);
  fm_main<<<512, 256, 0, stream>>>(x, w0, w1, vb, sh, out);
}